// Round 3
// baseline (42128.836 us; speedup 1.0000x reference)
//
#include <hip/hip_runtime.h>

typedef _Float16 f16;
typedef _Float16 h2 __attribute__((ext_vector_type(2)));

#define NBATCH 64
#define TSTEPS 1024
#define NH 256
#define N4H 1024
#define NWORDS 128      // half2 words per U column (256 rows / 2)
#define NRG 92          // words held in registers per column
#define NCHK 9          // LDS chunks of 4 words -> 36 words per column
#define BTROWS 65536
#define FSTR 44

#define OFF_FEAT 0ull
#define OFF_XZ   11534336ull      // 65536*44*4
#define OFF_H    145752064ull     // + 65536*1024*2
#define OFF_U2R  179306496ull     // + 65536*256*2
#define OFF_U2L  180879360ull     // + 3*131072*4
// total ws use: 181,321,728 bytes

#define SMEM_SCAN (NCHK*1024*16 + 4096 + 512 + 64)

__device__ __forceinline__ float fdot2_(h2 a, h2 b, float c) {
#if defined(__has_builtin) && __has_builtin(__builtin_amdgcn_fdot2)
  return __builtin_amdgcn_fdot2(a, b, c, false);
#else
  return c + (float)a.x * (float)b.x + (float)a.y * (float)b.y;
#endif
}

__device__ __forceinline__ float sigmf(float z) {
  return 1.f / (1.f + __expf(-z));
}

__device__ __forceinline__ float wave_sum64(float v) {
#pragma unroll
  for (int off = 32; off; off >>= 1) v += __shfl_xor(v, off);
  return v;
}

// ---------------- U conversion: f32 [256][1024] -> packed half2 ----------------
// Register part layout: U2r[w][j] = (U[2w][j], U[2w+1][j]),  w in [0,128)
__global__ __launch_bounds__(256) void cvt_u_reg(const float* __restrict__ U,
                                                 h2* __restrict__ dst) {
  int id = blockIdx.x * 256 + threadIdx.x;   // < 131072
  int w = id >> 10, j = id & 1023;
  h2 v;
  v.x = (f16)U[(2 * w) * 1024 + j];
  v.y = (f16)U[(2 * w + 1) * 1024 + j];
  dst[id] = v;
}

// LDS part layout: chunk c in [0,9), col j: float4 = words NRG+4c .. NRG+4c+3 of col j
__global__ __launch_bounds__(256) void cvt_u_lds(const float* __restrict__ U,
                                                 float4* __restrict__ dst) {
  int id = blockIdx.x * 256 + threadIdx.x;   // < 9216
  if (id >= NCHK * 1024) return;
  int c = id >> 10, j = id & 1023;
  alignas(16) h2 vv[4];
#pragma unroll
  for (int q = 0; q < 4; ++q) {
    int w = NRG + 4 * c + q;
    vv[q].x = (f16)U[(2 * w) * 1024 + j];
    vv[q].y = (f16)U[(2 * w + 1) * 1024 + j];
  }
  dst[id] = *(const float4*)vv;
}

// ---------------- embeddings -> feat [65536][44] (41 used) ----------------
__global__ __launch_bounds__(256) void embed_feat(
    const float* __restrict__ x,
    const float* __restrict__ pe_w1, const float* __restrict__ pe_b1,
    const float* __restrict__ pe_w2, const float* __restrict__ pe_b2,
    const float* __restrict__ te_w1, const float* __restrict__ te_b1,
    const float* __restrict__ te_w2, const float* __restrict__ te_b2,
    float* __restrict__ feat) {
  __shared__ float w[2548];
  const int tid = threadIdx.x;
  for (int i = tid; i < 595; i += 256) w[i] = te_w1[i];
  for (int i = tid; i < 17; i += 256) w[595 + i] = te_b1[i];
  for (int i = tid; i < 85; i += 256) w[612 + i] = te_w2[i];
  for (int i = tid; i < 5; i += 256) w[697 + i] = te_b2[i];
  for (int i = tid; i < 1539; i += 256) w[702 + i] = pe_w1[i];
  for (int i = tid; i < 27; i += 256) w[2241 + i] = pe_b1[i];
  for (int i = tid; i < 270; i += 256) w[2268 + i] = pe_w2[i];
  for (int i = tid; i < 10; i += 256) w[2538 + i] = pe_b2[i];
  __syncthreads();

  int row = blockIdx.x * 256 + tid;   // < 65536
  const float* xr = x + (size_t)row * 212;
  float* fr = feat + (size_t)row * FSTR;

  // team MLP 35 -> 17 -> 5
  {
    float h1[17];
#pragma unroll
    for (int h = 0; h < 17; ++h) h1[h] = w[595 + h];
    for (int k = 0; k < 35; ++k) {
      float xv = xr[k];
#pragma unroll
      for (int h = 0; h < 17; ++h) h1[h] += xv * w[k * 17 + h];
    }
#pragma unroll
    for (int h = 0; h < 17; ++h) h1[h] = fmaxf(h1[h], 0.f);
    float t2[5];
#pragma unroll
    for (int h = 0; h < 5; ++h) t2[h] = w[697 + h];
#pragma unroll
    for (int k = 0; k < 17; ++k) {
#pragma unroll
      for (int h = 0; h < 5; ++h) t2[h] += h1[k] * w[612 + k * 5 + h];
    }
#pragma unroll
    for (int h = 0; h < 5; ++h) fr[h] = fmaxf(t2[h], 0.f);
  }
  // player MLP 57 -> 27 -> 10, three slices s/a/bk
  for (int p = 0; p < 3; ++p) {
    const float* xp = xr + 35 + 57 * p;
    float h1[27];
#pragma unroll
    for (int h = 0; h < 27; ++h) h1[h] = w[2241 + h];
    for (int k = 0; k < 57; ++k) {
      float xv = xp[k];
#pragma unroll
      for (int h = 0; h < 27; ++h) h1[h] += xv * w[702 + k * 27 + h];
    }
#pragma unroll
    for (int h = 0; h < 27; ++h) h1[h] = fmaxf(h1[h], 0.f);
    float t2[10];
#pragma unroll
    for (int h = 0; h < 10; ++h) t2[h] = w[2538 + h];
#pragma unroll
    for (int k = 0; k < 27; ++k) {
#pragma unroll
      for (int h = 0; h < 10; ++h) t2[h] += h1[k] * w[2268 + k * 10 + h];
    }
#pragma unroll
    for (int h = 0; h < 10; ++h) fr[5 + 10 * p + h] = fmaxf(t2[h], 0.f);
  }
  // extra passthrough
#pragma unroll
  for (int e = 0; e < 6; ++e) fr[35 + e] = xr[206 + e];
}

// ---------------- xz1 = feat @ W1 + b  (K=41) -> f16 ----------------
__global__ __launch_bounds__(256) void gemm_feat(
    const float* __restrict__ feat, const float* __restrict__ W,
    const float* __restrict__ bias, f16* __restrict__ C) {
  __shared__ float Wl[41 * 256];
  __shared__ float fl[64 * FSTR];
  int m0 = blockIdx.x * 64, n0 = blockIdx.y * 256;
  int t = threadIdx.x;
  for (int r = 0; r < 41; ++r) Wl[r * 256 + t] = W[r * 1024 + n0 + t];
  for (int i = t; i < 64 * FSTR; i += 256) fl[i] = feat[(size_t)m0 * FSTR + i];
  __syncthreads();
  float bv = bias[n0 + t];
  for (int r = 0; r < 64; ++r) {
    float acc = bv;
#pragma unroll
    for (int k = 0; k < 41; ++k) acc += fl[r * FSTR + k] * Wl[k * 256 + t];
    C[(size_t)(m0 + r) * 1024 + n0 + t] = (f16)acc;
  }
}

// ---------------- xz = h_seq(f16) @ W(f32) + b -> f16   (K=256) ----------------
__global__ __launch_bounds__(256) void gemm_h(
    const f16* __restrict__ A, const float* __restrict__ B,
    const float* __restrict__ bias, f16* __restrict__ C) {
  __shared__ float As[32][72];
  __shared__ float Bs[32][64];
  int m0 = blockIdx.x * 64, n0 = blockIdx.y * 64;
  int t = threadIdx.x;
  int tx = t & 15, ty = t >> 4;
  float acc[4][4];
#pragma unroll
  for (int i = 0; i < 4; ++i)
#pragma unroll
    for (int j = 0; j < 4; ++j) acc[i][j] = 0.f;

  float bcol[4];
#pragma unroll
  for (int j = 0; j < 4; ++j) bcol[j] = bias[n0 + tx * 4 + j];

  for (int k0 = 0; k0 < 256; k0 += 32) {
    {
      int r = t >> 2, kq = (t & 3) * 8;
      const f16* ap = A + (size_t)(m0 + r) * 256 + k0 + kq;
      float4 raw = *(const float4*)ap;   // 8 halves
      const f16* hv = (const f16*)&raw;
#pragma unroll
      for (int q = 0; q < 8; ++q) As[kq + q][r] = (float)hv[q];
    }
    {
      int kr = t >> 3, nq = (t & 7) * 8;
      const float* bp = B + (size_t)(k0 + kr) * 1024 + n0 + nq;
      float4 b0 = *(const float4*)bp;
      float4 b1 = *(const float4*)(bp + 4);
      *(float4*)&Bs[kr][nq] = b0;
      *(float4*)&Bs[kr][nq + 4] = b1;
    }
    __syncthreads();
#pragma unroll
    for (int kk = 0; kk < 32; ++kk) {
      float4 av = *(const float4*)&As[kk][ty * 4];
      float4 bv = *(const float4*)&Bs[kk][tx * 4];
      const float* ap = (const float*)&av;
      const float* bp = (const float*)&bv;
#pragma unroll
      for (int i = 0; i < 4; ++i)
#pragma unroll
        for (int j = 0; j < 4; ++j) acc[i][j] += ap[i] * bp[j];
    }
    __syncthreads();
  }
#pragma unroll
  for (int i = 0; i < 4; ++i) {
    int row = m0 + ty * 4 + i;
    alignas(8) f16 ov[4];
#pragma unroll
    for (int j = 0; j < 4; ++j) ov[j] = (f16)(acc[i][j] + bcol[j]);
    *(uint2*)(C + (size_t)row * 1024 + n0 + tx * 4) = *(const uint2*)ov;
  }
}

// ---------------- recurrent scan: one workgroup per batch element ----------------
// 512 threads; thread t owns columns t (i/f gate) and t+512 (g/o gate).
// U (f16, packed half2 over k) resident: words [0,92) in VGPRs, words [92,128) in LDS.
// amdgpu_waves_per_eu(2,2): 512-thread block = 2 waves/SIMD (hard), so pin the
// allocator budget at 256 VGPRs — round-1 compiler chose 128 and spilled all of U.
__global__ __attribute__((amdgpu_flat_work_group_size(512, 512),
                          amdgpu_waves_per_eu(2, 2)))
void lstm_scan(
    const h2* __restrict__ U2r,      // [128][1024]
    const float4* __restrict__ U2l,  // [9][1024] chunks
    const f16* __restrict__ xz,      // [64][1024][1024]
    f16* __restrict__ hseq) {        // [64][1024][256]
  extern __shared__ char smem[];
  float4* uldsv = (float4*)smem;                       // 147456 B
  float* arr = (float*)(smem + 147456);                // 1024 f32
  f16* hsh = (f16*)(smem + 147456 + 4096);             // 256 f16
  float* red = (float*)(smem + 147456 + 4096 + 512);   // 16 f32

  const int bid = blockIdx.x;
  const int t = threadIdx.x;
  const bool lowhalf = (t < 256);

  // stage LDS-resident part of U
  for (int i = t; i < NCHK * 1024; i += 512) uldsv[i] = U2l[i];
  // load register-resident part of U
  h2 ua[NRG], ub[NRG];
#pragma unroll
  for (int w = 0; w < NRG; ++w) {
    ua[w] = U2r[w * 1024 + t];
    ub[w] = U2r[w * 1024 + t + 512];
  }
  if (lowhalf) hsh[t] = (f16)0.f;
  float creg = 0.f;
  __syncthreads();

#pragma unroll 1
  for (int step = 0; step < TSTEPS; ++step) {
    const f16* xzrow = xz + ((size_t)bid * TSTEPS + step) * 1024;
    float xza = (float)xzrow[t];
    float xzb = (float)xzrow[t + 512];

    float accA = 0.f, accA2 = 0.f, accB = 0.f, accB2 = 0.f;
    const float4* h4 = (const float4*)hsh;
#pragma unroll
    for (int q = 0; q < NRG / 4; ++q) {   // words 0..91
      float4 hw = h4[q];
      const h2* hp = (const h2*)&hw;
      accA = fdot2_(ua[4 * q + 0], hp[0], accA);
      accA2 = fdot2_(ua[4 * q + 1], hp[1], accA2);
      accA = fdot2_(ua[4 * q + 2], hp[2], accA);
      accA2 = fdot2_(ua[4 * q + 3], hp[3], accA2);
      accB = fdot2_(ub[4 * q + 0], hp[0], accB);
      accB2 = fdot2_(ub[4 * q + 1], hp[1], accB2);
      accB = fdot2_(ub[4 * q + 2], hp[2], accB);
      accB2 = fdot2_(ub[4 * q + 3], hp[3], accB2);
    }
#pragma unroll
    for (int c = 0; c < NCHK; ++c) {      // words 92..127
      float4 ta = uldsv[c * 1024 + t];
      float4 tb = uldsv[c * 1024 + t + 512];
      float4 hw = h4[NRG / 4 + c];
      const h2* hp = (const h2*)&hw;
      const h2* pa = (const h2*)&ta;
      const h2* pb = (const h2*)&tb;
      accA = fdot2_(pa[0], hp[0], accA);
      accA2 = fdot2_(pa[1], hp[1], accA2);
      accA = fdot2_(pa[2], hp[2], accA);
      accA2 = fdot2_(pa[3], hp[3], accA2);
      accB = fdot2_(pb[0], hp[0], accB);
      accB2 = fdot2_(pb[1], hp[1], accB2);
      accB = fdot2_(pb[2], hp[2], accB);
      accB2 = fdot2_(pb[3], hp[3], accB2);
    }
    float za = xza + accA + accA2;    // col t:      i (low) / f (high)
    float zb = xzb + accB + accB2;    // col t+512:  g (low) / o (high)

    float sa = sigmf(za);
    float ab = lowhalf ? __expf(zb) : sigmf(zb);
    arr[t] = sa;
    arr[t + 512] = ab;

    if (lowhalf) {                    // g-gate exp sum (cols 512..767)
      float gs = wave_sum64(ab);
      if ((t & 63) == 0) red[t >> 6] = gs;
    }
    __syncthreads();

    float ec = 0.f;
    if (lowhalf) {
      float gsum = red[0] + red[1] + red[2] + red[3];
      float smg = ab / gsum;          // own g column is k=t
      creg = arr[256 + t] * creg + sa * smg;   // sig(f)*c + sig(i)*softmax(g)
      ec = __expf(creg);
      float cs = wave_sum64(ec);
      if ((t & 63) == 0) red[8 + (t >> 6)] = cs;
    }
    __syncthreads();

    if (lowhalf) {
      float csum = red[8] + red[9] + red[10] + red[11];
      float hv = arr[768 + t] * (ec / csum);   // sig(o)*softmax(c)
      hsh[t] = (f16)hv;
      hseq[((size_t)bid * TSTEPS + step) * NH + t] = (f16)hv;
    }
    __syncthreads();
  }
}

// ---------------- head: dense 256->100->40->2 + softmax ----------------
__global__ __launch_bounds__(128) void head_k(
    const f16* __restrict__ hseq,
    const float* __restrict__ d1w, const float* __restrict__ d1b,
    const float* __restrict__ d2w, const float* __restrict__ d2b,
    const float* __restrict__ d3w, const float* __restrict__ d3b,
    float* __restrict__ out) {
  __shared__ float hl[256], o1[100], o2[40];
  int b = blockIdx.x, t = threadIdx.x;
  const f16* hrow = hseq + ((size_t)b * TSTEPS + (TSTEPS - 1)) * NH;
  for (int i = t; i < 256; i += 128) hl[i] = (float)hrow[i];
  __syncthreads();
  if (t < 100) {
    float acc = d1b[t];
    for (int k = 0; k < 256; ++k) acc += hl[k] * d1w[k * 100 + t];
    o1[t] = fmaxf(acc, 0.f);
  }
  __syncthreads();
  if (t < 40) {
    float acc = d2b[t];
    for (int k = 0; k < 100; ++k) acc += o1[k] * d2w[k * 40 + t];
    o2[t] = fmaxf(acc, 0.f);
  }
  __syncthreads();
  if (t == 0) {
    float a0 = d3b[0], a1 = d3b[1];
    for (int k = 0; k < 40; ++k) {
      a0 += o2[k] * d3w[k * 2];
      a1 += o2[k] * d3w[k * 2 + 1];
    }
    float m = fmaxf(a0, a1);
    float e0 = __expf(a0 - m), e1 = __expf(a1 - m);
    float s = e0 + e1;
    out[b * 2] = e0 / s;
    out[b * 2 + 1] = e1 / s;
  }
}

extern "C" void kernel_launch(void* const* d_in, const int* in_sizes, int n_in,
                              void* d_out, int out_size, void* d_ws, size_t ws_size,
                              hipStream_t stream) {
  const float* x = (const float*)d_in[0];
  const float* pe_w1 = (const float*)d_in[1];
  const float* pe_b1 = (const float*)d_in[2];
  const float* pe_w2 = (const float*)d_in[3];
  const float* pe_b2 = (const float*)d_in[4];
  const float* te_w1 = (const float*)d_in[5];
  const float* te_b1 = (const float*)d_in[6];
  const float* te_w2 = (const float*)d_in[7];
  const float* te_b2 = (const float*)d_in[8];
  const float* W1 = (const float*)d_in[9];
  const float* U1 = (const float*)d_in[10];
  const float* bl1 = (const float*)d_in[11];
  const float* W2 = (const float*)d_in[12];
  const float* U2m = (const float*)d_in[13];
  const float* bl2 = (const float*)d_in[14];
  const float* W3 = (const float*)d_in[15];
  const float* U3 = (const float*)d_in[16];
  const float* bl3 = (const float*)d_in[17];
  const float* d1w = (const float*)d_in[18];
  const float* d1b = (const float*)d_in[19];
  const float* d2w = (const float*)d_in[20];
  const float* d2b = (const float*)d_in[21];
  const float* d3w = (const float*)d_in[22];
  const float* d3b = (const float*)d_in[23];
  float* out = (float*)d_out;

  char* ws = (char*)d_ws;
  float* feat = (float*)(ws + OFF_FEAT);
  f16* xzbuf = (f16*)(ws + OFF_XZ);
  f16* hseq = (f16*)(ws + OFF_H);
  h2* u2r = (h2*)(ws + OFF_U2R);
  float4* u2l = (float4*)(ws + OFF_U2L);

  hipFuncSetAttribute((const void*)lstm_scan,
                      hipFuncAttributeMaxDynamicSharedMemorySize, SMEM_SCAN);

  const float* Us[3] = {U1, U2m, U3};
  for (int l = 0; l < 3; ++l) {
    cvt_u_reg<<<512, 256, 0, stream>>>(Us[l], u2r + (size_t)l * 131072);
    cvt_u_lds<<<36, 256, 0, stream>>>(Us[l], u2l + (size_t)l * (NCHK * 1024));
  }

  embed_feat<<<256, 256, 0, stream>>>(x, pe_w1, pe_b1, pe_w2, pe_b2,
                                      te_w1, te_b1, te_w2, te_b2, feat);
  gemm_feat<<<dim3(1024, 4), 256, 0, stream>>>(feat, W1, bl1, xzbuf);
  lstm_scan<<<64, 512, SMEM_SCAN, stream>>>(u2r, u2l, xzbuf, hseq);

  gemm_h<<<dim3(1024, 16), 256, 0, stream>>>(hseq, W2, bl2, xzbuf);
  lstm_scan<<<64, 512, SMEM_SCAN, stream>>>(u2r + 131072, u2l + NCHK * 1024,
                                            xzbuf, hseq);

  gemm_h<<<dim3(1024, 16), 256, 0, stream>>>(hseq, W3, bl3, xzbuf);
  lstm_scan<<<64, 512, SMEM_SCAN, stream>>>(u2r + 2 * 131072, u2l + 2 * NCHK * 1024,
                                            xzbuf, hseq);

  head_k<<<64, 128, 0, stream>>>(hseq, d1w, d1b, d2w, d2b, d3w, d3b, out);
}

// Round 4
// 16141.512 us; speedup vs baseline: 2.6100x; 2.6100x over previous
//
#include <hip/hip_runtime.h>

typedef _Float16 f16;
typedef _Float16 h2 __attribute__((ext_vector_type(2)));

#define NBATCH 64
#define TSTEPS 1024
#define NH 256
#define FSTR 44

#define OFF_FEAT 0ull
#define OFF_XZ   11534336ull      // 65536*44*4
#define OFF_H    145752064ull     // + 65536*1024*2
#define OFF_UPK  179306496ull     // + 65536*256*2 ; 3 layers * 512KB = 1.5MB
// total ws use: 180,879,360 bytes

__device__ __forceinline__ float fdot2_(h2 a, h2 b, float c) {
#if defined(__has_builtin) && __has_builtin(__builtin_amdgcn_fdot2)
  return __builtin_amdgcn_fdot2(a, b, c, false);
#else
  return c + (float)a.x * (float)b.x + (float)a.y * (float)b.y;
#endif
}

__device__ __forceinline__ float sigmf(float z) {
  return 1.f / (1.f + __expf(-z));
}

__device__ __forceinline__ float wave_sum64(float v) {
#pragma unroll
  for (int off = 32; off; off >>= 1) v += __shfl_xor(v, off);
  return v;
}

// ---- U conversion: f32 [256][1024] -> interleaved packed-h2 float4 ----
// Upk[q*1024 + c] = {h2(U[8q][c],U[8q+1][c]), h2(U[8q+2][c],U[8q+3][c]),
//                    h2(U[8q+4][c],U[8q+5][c]), h2(U[8q+6][c],U[8q+7][c])}
// i.e. k-words 4q..4q+3 of column c. Lane c, lane c+1 -> adjacent 16B: coalesced.
__global__ __launch_bounds__(256) void cvt_u_pk(const float* __restrict__ U,
                                                float4* __restrict__ dst) {
  int id = blockIdx.x * 256 + threadIdx.x;   // < 32768
  int q = id >> 10, c = id & 1023;
  alignas(16) h2 vv[4];
#pragma unroll
  for (int j = 0; j < 4; ++j) {
    int w = 4 * q + j;
    vv[j].x = (f16)U[(2 * w) * 1024 + c];
    vv[j].y = (f16)U[(2 * w + 1) * 1024 + c];
  }
  dst[id] = *(const float4*)vv;
}

// ---------------- embeddings -> feat [65536][44] (41 used) ----------------
__global__ __launch_bounds__(256) void embed_feat(
    const float* __restrict__ x,
    const float* __restrict__ pe_w1, const float* __restrict__ pe_b1,
    const float* __restrict__ pe_w2, const float* __restrict__ pe_b2,
    const float* __restrict__ te_w1, const float* __restrict__ te_b1,
    const float* __restrict__ te_w2, const float* __restrict__ te_b2,
    float* __restrict__ feat) {
  __shared__ float w[2548];
  const int tid = threadIdx.x;
  for (int i = tid; i < 595; i += 256) w[i] = te_w1[i];
  for (int i = tid; i < 17; i += 256) w[595 + i] = te_b1[i];
  for (int i = tid; i < 85; i += 256) w[612 + i] = te_w2[i];
  for (int i = tid; i < 5; i += 256) w[697 + i] = te_b2[i];
  for (int i = tid; i < 1539; i += 256) w[702 + i] = pe_w1[i];
  for (int i = tid; i < 27; i += 256) w[2241 + i] = pe_b1[i];
  for (int i = tid; i < 270; i += 256) w[2268 + i] = pe_w2[i];
  for (int i = tid; i < 10; i += 256) w[2538 + i] = pe_b2[i];
  __syncthreads();

  int row = blockIdx.x * 256 + tid;   // < 65536
  const float* xr = x + (size_t)row * 212;
  float* fr = feat + (size_t)row * FSTR;

  // team MLP 35 -> 17 -> 5
  {
    float h1[17];
#pragma unroll
    for (int h = 0; h < 17; ++h) h1[h] = w[595 + h];
    for (int k = 0; k < 35; ++k) {
      float xv = xr[k];
#pragma unroll
      for (int h = 0; h < 17; ++h) h1[h] += xv * w[k * 17 + h];
    }
#pragma unroll
    for (int h = 0; h < 17; ++h) h1[h] = fmaxf(h1[h], 0.f);
    float t2[5];
#pragma unroll
    for (int h = 0; h < 5; ++h) t2[h] = w[697 + h];
#pragma unroll
    for (int k = 0; k < 17; ++k) {
#pragma unroll
      for (int h = 0; h < 5; ++h) t2[h] += h1[k] * w[612 + k * 5 + h];
    }
#pragma unroll
    for (int h = 0; h < 5; ++h) fr[h] = fmaxf(t2[h], 0.f);
  }
  // player MLP 57 -> 27 -> 10, three slices s/a/bk
  for (int p = 0; p < 3; ++p) {
    const float* xp = xr + 35 + 57 * p;
    float h1[27];
#pragma unroll
    for (int h = 0; h < 27; ++h) h1[h] = w[2241 + h];
    for (int k = 0; k < 57; ++k) {
      float xv = xp[k];
#pragma unroll
      for (int h = 0; h < 27; ++h) h1[h] += xv * w[702 + k * 27 + h];
    }
#pragma unroll
    for (int h = 0; h < 27; ++h) h1[h] = fmaxf(h1[h], 0.f);
    float t2[10];
#pragma unroll
    for (int h = 0; h < 10; ++h) t2[h] = w[2538 + h];
#pragma unroll
    for (int k = 0; k < 27; ++k) {
#pragma unroll
      for (int h = 0; h < 10; ++h) t2[h] += h1[k] * w[2268 + k * 10 + h];
    }
#pragma unroll
    for (int h = 0; h < 10; ++h) fr[5 + 10 * p + h] = fmaxf(t2[h], 0.f);
  }
  // extra passthrough
#pragma unroll
  for (int e = 0; e < 6; ++e) fr[35 + e] = xr[206 + e];
}

// ---------------- xz1 = feat @ W1 + b  (K=41) -> f16 ----------------
__global__ __launch_bounds__(256) void gemm_feat(
    const float* __restrict__ feat, const float* __restrict__ W,
    const float* __restrict__ bias, f16* __restrict__ C) {
  __shared__ float Wl[41 * 256];
  __shared__ float fl[64 * FSTR];
  int m0 = blockIdx.x * 64, n0 = blockIdx.y * 256;
  int t = threadIdx.x;
  for (int r = 0; r < 41; ++r) Wl[r * 256 + t] = W[r * 1024 + n0 + t];
  for (int i = t; i < 64 * FSTR; i += 256) fl[i] = feat[(size_t)m0 * FSTR + i];
  __syncthreads();
  float bv = bias[n0 + t];
  for (int r = 0; r < 64; ++r) {
    float acc = bv;
#pragma unroll
    for (int k = 0; k < 41; ++k) acc += fl[r * FSTR + k] * Wl[k * 256 + t];
    C[(size_t)(m0 + r) * 1024 + n0 + t] = (f16)acc;
  }
}

// ---------------- xz = h_seq(f16) @ W(f32) + b -> f16   (K=256) ----------------
__global__ __launch_bounds__(256) void gemm_h(
    const f16* __restrict__ A, const float* __restrict__ B,
    const float* __restrict__ bias, f16* __restrict__ C) {
  __shared__ float As[32][72];
  __shared__ float Bs[32][64];
  int m0 = blockIdx.x * 64, n0 = blockIdx.y * 64;
  int t = threadIdx.x;
  int tx = t & 15, ty = t >> 4;
  float acc[4][4];
#pragma unroll
  for (int i = 0; i < 4; ++i)
#pragma unroll
    for (int j = 0; j < 4; ++j) acc[i][j] = 0.f;

  float bcol[4];
#pragma unroll
  for (int j = 0; j < 4; ++j) bcol[j] = bias[n0 + tx * 4 + j];

  for (int k0 = 0; k0 < 256; k0 += 32) {
    {
      int r = t >> 2, kq = (t & 3) * 8;
      const f16* ap = A + (size_t)(m0 + r) * 256 + k0 + kq;
      float4 raw = *(const float4*)ap;   // 8 halves
      const f16* hv = (const f16*)&raw;
#pragma unroll
      for (int q = 0; q < 8; ++q) As[kq + q][r] = (float)hv[q];
    }
    {
      int kr = t >> 3, nq = (t & 7) * 8;
      const float* bp = B + (size_t)(k0 + kr) * 1024 + n0 + nq;
      float4 b0 = *(const float4*)bp;
      float4 b1 = *(const float4*)(bp + 4);
      *(float4*)&Bs[kr][nq] = b0;
      *(float4*)&Bs[kr][nq + 4] = b1;
    }
    __syncthreads();
#pragma unroll
    for (int kk = 0; kk < 32; ++kk) {
      float4 av = *(const float4*)&As[kk][ty * 4];
      float4 bv = *(const float4*)&Bs[kk][tx * 4];
      const float* ap = (const float*)&av;
      const float* bp = (const float*)&bv;
#pragma unroll
      for (int i = 0; i < 4; ++i)
#pragma unroll
        for (int j = 0; j < 4; ++j) acc[i][j] += ap[i] * bp[j];
    }
    __syncthreads();
  }
#pragma unroll
  for (int i = 0; i < 4; ++i) {
    int row = m0 + ty * 4 + i;
    alignas(8) f16 ov[4];
#pragma unroll
    for (int j = 0; j < 4; ++j) ov[j] = (f16)(acc[i][j] + bcol[j]);
    *(uint2*)(C + (size_t)row * 1024 + n0 + tx * 4) = *(const uint2*)ov;
  }
}

// ---------------- recurrent scan: one workgroup per batch element ----------------
// 512 threads; thread t owns columns t (i/f gate) and t+512 (g/o gate).
// U is STREAMED from per-XCD L2 every step (512 KB read-only working set,
// shared by the ~8 blocks on an XCD). No per-thread arrays -> nothing spills.
// h is broadcast via wave-uniform ds_read_b128 (free broadcast path).
__global__ __launch_bounds__(512) void lstm_scan_s(
    const float4* __restrict__ Upk,  // [32][1024] float4, layer-specific
    const f16* __restrict__ xz,      // [64][1024][1024]
    f16* __restrict__ hseq) {        // [64][1024][256]
  __shared__ float4 h4s[32];                  // h packed as 128 h2
  __shared__ float arr[1024];
  __shared__ float red[16];
  f16* hsh = (f16*)h4s;

  const int bid = blockIdx.x;
  const int t = threadIdx.x;
  const bool lowhalf = (t < 256);

  if (t < 32) h4s[t] = float4{0.f, 0.f, 0.f, 0.f};
  float creg = 0.f;
  __syncthreads();

#pragma unroll 1
  for (int step = 0; step < TSTEPS; ++step) {
    const f16* xzrow = xz + ((size_t)bid * TSTEPS + step) * 1024;
    float xza = (float)xzrow[t];
    float xzb = (float)xzrow[t + 512];

    float accA = 0.f, accA2 = 0.f, accB = 0.f, accB2 = 0.f;
#pragma unroll 8
    for (int q = 0; q < 32; ++q) {
      float4 ua = Upk[q * 1024 + t];          // col t, k-words 4q..4q+3
      float4 ub = Upk[q * 1024 + t + 512];    // col t+512
      float4 hw = h4s[q];                     // wave-uniform broadcast read
      const h2* ha = (const h2*)&hw;
      const h2* pa = (const h2*)&ua;
      const h2* pb = (const h2*)&ub;
      accA  = fdot2_(pa[0], ha[0], accA);
      accA2 = fdot2_(pa[1], ha[1], accA2);
      accA  = fdot2_(pa[2], ha[2], accA);
      accA2 = fdot2_(pa[3], ha[3], accA2);
      accB  = fdot2_(pb[0], ha[0], accB);
      accB2 = fdot2_(pb[1], ha[1], accB2);
      accB  = fdot2_(pb[2], ha[2], accB);
      accB2 = fdot2_(pb[3], ha[3], accB2);
    }
    float za = xza + accA + accA2;    // col t:      i (low) / f (high)
    float zb = xzb + accB + accB2;    // col t+512:  g (low) / o (high)

    float sa = sigmf(za);
    float ab = lowhalf ? __expf(zb) : sigmf(zb);
    arr[t] = sa;
    arr[t + 512] = ab;

    if (lowhalf) {                    // g-gate exp sum (cols 512..767)
      float gs = wave_sum64(ab);
      if ((t & 63) == 0) red[t >> 6] = gs;
    }
    __syncthreads();

    float ec = 0.f;
    if (lowhalf) {
      float gsum = red[0] + red[1] + red[2] + red[3];
      float smg = ab / gsum;          // own g column is k=t
      creg = arr[256 + t] * creg + sa * smg;   // sig(f)*c + sig(i)*softmax(g)
      ec = __expf(creg);
      float cs = wave_sum64(ec);
      if ((t & 63) == 0) red[8 + (t >> 6)] = cs;
    }
    __syncthreads();

    if (lowhalf) {
      float csum = red[8] + red[9] + red[10] + red[11];
      float hv = arr[768 + t] * (ec / csum);   // sig(o)*softmax(c)
      hsh[t] = (f16)hv;
      hseq[((size_t)bid * TSTEPS + step) * NH + t] = (f16)hv;
    }
    __syncthreads();
  }
}

// ---------------- head: dense 256->100->40->2 + softmax ----------------
__global__ __launch_bounds__(128) void head_k(
    const f16* __restrict__ hseq,
    const float* __restrict__ d1w, const float* __restrict__ d1b,
    const float* __restrict__ d2w, const float* __restrict__ d2b,
    const float* __restrict__ d3w, const float* __restrict__ d3b,
    float* __restrict__ out) {
  __shared__ float hl[256], o1[100], o2[40];
  int b = blockIdx.x, t = threadIdx.x;
  const f16* hrow = hseq + ((size_t)b * TSTEPS + (TSTEPS - 1)) * NH;
  for (int i = t; i < 256; i += 128) hl[i] = (float)hrow[i];
  __syncthreads();
  if (t < 100) {
    float acc = d1b[t];
    for (int k = 0; k < 256; ++k) acc += hl[k] * d1w[k * 100 + t];
    o1[t] = fmaxf(acc, 0.f);
  }
  __syncthreads();
  if (t < 40) {
    float acc = d2b[t];
    for (int k = 0; k < 100; ++k) acc += o1[k] * d2w[k * 40 + t];
    o2[t] = fmaxf(acc, 0.f);
  }
  __syncthreads();
  if (t == 0) {
    float a0 = d3b[0], a1 = d3b[1];
    for (int k = 0; k < 40; ++k) {
      a0 += o2[k] * d3w[k * 2];
      a1 += o2[k] * d3w[k * 2 + 1];
    }
    float m = fmaxf(a0, a1);
    float e0 = __expf(a0 - m), e1 = __expf(a1 - m);
    float s = e0 + e1;
    out[b * 2] = e0 / s;
    out[b * 2 + 1] = e1 / s;
  }
}

extern "C" void kernel_launch(void* const* d_in, const int* in_sizes, int n_in,
                              void* d_out, int out_size, void* d_ws, size_t ws_size,
                              hipStream_t stream) {
  const float* x = (const float*)d_in[0];
  const float* pe_w1 = (const float*)d_in[1];
  const float* pe_b1 = (const float*)d_in[2];
  const float* pe_w2 = (const float*)d_in[3];
  const float* pe_b2 = (const float*)d_in[4];
  const float* te_w1 = (const float*)d_in[5];
  const float* te_b1 = (const float*)d_in[6];
  const float* te_w2 = (const float*)d_in[7];
  const float* te_b2 = (const float*)d_in[8];
  const float* W1 = (const float*)d_in[9];
  const float* U1 = (const float*)d_in[10];
  const float* bl1 = (const float*)d_in[11];
  const float* W2 = (const float*)d_in[12];
  const float* U2m = (const float*)d_in[13];
  const float* bl2 = (const float*)d_in[14];
  const float* W3 = (const float*)d_in[15];
  const float* U3 = (const float*)d_in[16];
  const float* bl3 = (const float*)d_in[17];
  const float* d1w = (const float*)d_in[18];
  const float* d1b = (const float*)d_in[19];
  const float* d2w = (const float*)d_in[20];
  const float* d2b = (const float*)d_in[21];
  const float* d3w = (const float*)d_in[22];
  const float* d3b = (const float*)d_in[23];
  float* out = (float*)d_out;

  char* ws = (char*)d_ws;
  float* feat = (float*)(ws + OFF_FEAT);
  f16* xzbuf = (f16*)(ws + OFF_XZ);
  f16* hseq = (f16*)(ws + OFF_H);
  float4* upk = (float4*)(ws + OFF_UPK);   // 3 layers x 32768 float4

  const float* Us[3] = {U1, U2m, U3};
  for (int l = 0; l < 3; ++l)
    cvt_u_pk<<<128, 256, 0, stream>>>(Us[l], upk + (size_t)l * 32768);

  embed_feat<<<256, 256, 0, stream>>>(x, pe_w1, pe_b1, pe_w2, pe_b2,
                                      te_w1, te_b1, te_w2, te_b2, feat);
  gemm_feat<<<dim3(1024, 4), 256, 0, stream>>>(feat, W1, bl1, xzbuf);
  lstm_scan_s<<<64, 512, 0, stream>>>(upk, xzbuf, hseq);

  gemm_h<<<dim3(1024, 16), 256, 0, stream>>>(hseq, W2, bl2, xzbuf);
  lstm_scan_s<<<64, 512, 0, stream>>>(upk + 32768, xzbuf, hseq);

  gemm_h<<<dim3(1024, 16), 256, 0, stream>>>(hseq, W3, bl3, xzbuf);
  lstm_scan_s<<<64, 512, 0, stream>>>(upk + 2 * 32768, xzbuf, hseq);

  head_k<<<64, 128, 0, stream>>>(hseq, d1w, d1b, d2w, d2b, d3w, d3b, out);
}